// Round 17
// baseline (549.455 us; speedup 1.0000x reference)
//
#include <hip/hip_runtime.h>
#include <hip/hip_bf16.h>

typedef __hip_bfloat16 bf16;
typedef __attribute__((ext_vector_type(4))) float f32x4;
typedef __attribute__((ext_vector_type(8))) __bf16 bf16x8;
typedef __attribute__((ext_vector_type(4))) __bf16 bf16x4;

constexpr int NB  = 8;
constexpr int NHH = 128;
constexpr int NWW = 128;
constexpr int NE  = 192;
constexpr int ND  = 576;
constexpr int NR  = 512;
constexpr int NL  = 256;
constexpr int NP  = NB * NHH * NWW;   // 131072
constexpr int NPC = NHH * NWW;        // 16384

__device__ __forceinline__ void gload16(const void* g, void* l) {
    __builtin_amdgcn_global_load_lds(
        (const __attribute__((address_space(1))) unsigned int*)g,
        (__attribute__((address_space(3))) unsigned int*)l, 16, 0, 0);
}

// ---------------- merged: RPE pos (b<512) + RPE weight transpose ----------------
__global__ __launch_bounds__(256) void k_pre1(
    const float* __restrict__ pw1, const float* __restrict__ pb1,
    const float* __restrict__ pw2, const float* __restrict__ pb2,
    const float* __restrict__ lw1, const float* __restrict__ ow1,
    const float* __restrict__ lw2, const float* __restrict__ ow2,
    float* __restrict__ h, float* __restrict__ wt)
{
    __shared__ float tile[32][33];
    int b = blockIdx.x;
    if (b < 512) {
        int net = b >> 8, l = b & 255;
        const float* pw = net ? pw2 : pw1;
        const float* pb = net ? pb2 : pb1;
        float idxv;
        if (l == 0 || l == 128) idxv = 0.f;
        else if (l < 128)       idxv = (float)l;
        else                    idxv = (float)(l - 256);
        float* hr = h + ((size_t)net * NL + l) * NR;
        for (int r = threadIdx.x; r < NR; r += 256)
            hr[r] = idxv * pw[r] + pb[r];
    } else {
        int idx = b - 512;                 // 2304 blocks: m(8) x jb(18) x rb(16)
        int m = idx / 288;
        int rem = idx - m * 288;
        int jb = rem >> 4, rb = rem & 15;
        int net = m >> 2, sub = m & 3;
        int J = (sub == 3) ? 576 : 512;
        const float* src = (sub == 3) ? (net ? ow2 : ow1)
                                      : (net ? lw2 : lw1) + (size_t)sub * 262144;
        float* dst = wt + (size_t)net * 1081344 + ((sub == 3) ? 786432 : sub * 262144);
        int r0 = rb * 32, j0 = jb * 32;
        if (j0 >= J) return;
        int tx = threadIdx.x & 31, ty = threadIdx.x >> 5;
        #pragma unroll
        for (int d = 0; d < 4; ++d) {
            int j = j0 + ty + d * 8;
            tile[ty + d * 8][tx] = (j < J) ? src[(size_t)j * 512 + r0 + tx] : 0.f;
        }
        __syncthreads();
        #pragma unroll
        for (int d = 0; d < 4; ++d) {
            int r = r0 + ty + d * 8;
            int j = j0 + tx;
            if (j < J) dst[(size_t)r * J + j] = tile[tx][ty + d * 8];
        }
    }
}

// ---------------- RPE layer: out = relu(srms(h)) @ Wt + b ----------------
__global__ __launch_bounds__(256) void k_rpe_layer(
    const float* __restrict__ hin,
    const float* __restrict__ Wt1, const float* __restrict__ b1,
    const float* __restrict__ Wt2, const float* __restrict__ b2,
    float* __restrict__ out1, float* __restrict__ out2, int outdim)
{
    __shared__ float g[2][NR];
    __shared__ float red[256];
    int net = blockIdx.x >> 7;
    int l0  = (blockIdx.x & 127) * 2;
    const float* hr = hin + ((size_t)net * NL + l0) * NR;
    int tid = threadIdx.x;
    int row = tid >> 7, ix = tid & 127;
    const float* hh = hr + (size_t)row * NR;
    float a0 = hh[ix], a1 = hh[ix + 128], a2 = hh[ix + 256], a3 = hh[ix + 384];
    red[tid] = a0 * a0 + a1 * a1 + a2 * a2 + a3 * a3;
    __syncthreads();
    for (int off = 64; off; off >>= 1) {
        if (ix < off) red[tid] += red[tid + off];
        __syncthreads();
    }
    float sc = 1.f / (sqrtf(red[row << 7]) * 0.044194173824159216f + 1e-8f);  // d=512
    g[row][ix]       = fmaxf(a0 * sc, 0.f);
    g[row][ix + 128] = fmaxf(a1 * sc, 0.f);
    g[row][ix + 256] = fmaxf(a2 * sc, 0.f);
    g[row][ix + 384] = fmaxf(a3 * sc, 0.f);
    __syncthreads();
    const float* Wt = net ? Wt2 : Wt1;
    const float* bb = net ? b2 : b1;
    float* o0 = (net ? out2 : out1) + (size_t)l0 * outdim;
    int half = outdim >> 1;
    for (int jj = tid; jj < half; jj += 256) {
        float ax0 = 0.f, ay0 = 0.f, ax1 = 0.f, ay1 = 0.f;
        const float* wp = Wt + 2 * jj;
        #pragma unroll 8
        for (int r = 0; r < NR; ++r) {
            float2 w = *(const float2*)(wp + (size_t)r * outdim);
            float g0 = g[0][r], g1 = g[1][r];
            ax0 = fmaf(g0, w.x, ax0); ay0 = fmaf(g0, w.y, ay0);
            ax1 = fmaf(g1, w.x, ax1); ay1 = fmaf(g1, w.y, ay1);
        }
        float bx = bb[2 * jj], by = bb[2 * jj + 1];
        o0[2 * jj]              = ax0 + bx;  o0[2 * jj + 1]          = ay0 + by;
        o0[outdim + 2 * jj]     = ax1 + bx;  o0[outdim + 2 * jj + 1] = ay1 + by;
    }
}

// ---------------- merged: prep (b<32768) + toep + wconv ----------------
__global__ __launch_bounds__(256) void k_pre2(
    const float* __restrict__ x, bf16* __restrict__ xbn,
    const float* __restrict__ A1, const float* __restrict__ A2, bf16* __restrict__ T,
    const float* __restrict__ uw, const float* __restrict__ vw,
    const float* __restrict__ ow, bf16* __restrict__ wb, bf16* __restrict__ owb)
{
    __shared__ __align__(16) char sm[17408];
    int b = blockIdx.x;
    int tid = threadIdx.x;
    if (b < 32768) {
        __bf16 (*wbuf)[208] = (__bf16(*)[208])sm;
        int w = tid >> 6, lane = tid & 63;
        int p = b * 4 + w;
        const float* xp = x + (size_t)p * NE;
        float v0 = xp[lane], v1 = xp[lane + 64], v2 = xp[lane + 128];
        float ss = v0 * v0 + v1 * v1 + v2 * v2;
        for (int off = 32; off; off >>= 1) ss += __shfl_xor(ss, off, 64);
        float sc = __builtin_amdgcn_rcpf(sqrtf(ss) * 0.07216878364870323f + 1e-8f);
        wbuf[w][lane]       = (__bf16)(v0 * sc);
        wbuf[w][lane + 64]  = (__bf16)(v1 * sc);
        wbuf[w][lane + 128] = (__bf16)(v2 * sc);
        __syncthreads();
        if (lane < 24) {
            bf16x8 o = *(bf16x8*)&wbuf[w][lane * 8];
            int t = (lane & 24) | ((lane & 7) ^ (p & 7));
            *(bf16x8*)((__bf16*)xbn + (size_t)p * NE + t * 8) = o;
        }
    } else if (b < 32768 + 288) {
        float (*Als)[17] = (float(*)[17])sm;
        int i = b - 32768;
        int cb = i % 36, rq = (i / 36) & 3, net = i / 144;
        const float* A = net ? A2 : A1;
        #pragma unroll
        for (int it = 0; it < 16; ++it) {
            int el = it * 256 + tid;
            int k = el >> 4, cl = el & 15;
            Als[k][cl] = A[(size_t)k * ND + cb * 16 + cl];
        }
        __syncthreads();
        int cl = tid >> 4, sg = tid & 15;
        __bf16* Tb = (__bf16*)T + (((size_t)net * ND + cb * 16 + cl) * 128) * 128;
        for (int rr = 0; rr < 32; ++rr) {
            int r = rq * 32 + rr;
            bf16x8 o;
            #pragma unroll
            for (int j = 0; j < 8; ++j)
                o[j] = (__bf16)Als[(r - sg * 8 - j) & 255][cl];
            *(bf16x8*)(Tb + (size_t)r * 128 + sg * 8) = o;
        }
    } else {
        int gid = (b - 33056) * 256 + tid;
        if (gid < 27648) {
            int row = gid / 24, bb = gid - row * 24;
            const float* src = ((row < ND) ? uw + (size_t)row * NE
                                           : vw + (size_t)(row - ND) * NE) + bb * 8;
            float4 f0 = ((const float4*)src)[0], f1 = ((const float4*)src)[1];
            bf16x8 o;
            o[0] = (__bf16)f0.x; o[1] = (__bf16)f0.y; o[2] = (__bf16)f0.z; o[3] = (__bf16)f0.w;
            o[4] = (__bf16)f1.x; o[5] = (__bf16)f1.y; o[6] = (__bf16)f1.z; o[7] = (__bf16)f1.w;
            int t = (bb & 24) | ((bb & 7) ^ (row & 7));
            *(bf16x8*)((__bf16*)wb + (size_t)row * NE + t * 8) = o;
        } else if (gid < 27648 + 13824) {
            int g = gid - 27648;
            const float* src = ow + (size_t)g * 8;
            float4 f0 = ((const float4*)src)[0], f1 = ((const float4*)src)[1];
            bf16x8 o;
            o[0] = (__bf16)f0.x; o[1] = (__bf16)f0.y; o[2] = (__bf16)f0.z; o[3] = (__bf16)f0.w;
            o[4] = (__bf16)f1.x; o[5] = (__bf16)f1.y; o[6] = (__bf16)f1.z; o[7] = (__bf16)f1.w;
            *(bf16x8*)((__bf16*)owb + (size_t)g * 8) = o;
        }
    }
}

// ---------------- u,v MFMA GEMM (all chunks), channel-major output ----------------
// 2-pass epilogue, smem exactly 32768 -> 5 blocks/CU (r10-proven best for k_uv).
__global__ __launch_bounds__(256, 4) void k_uv(
    const bf16* __restrict__ xbn, const bf16* __restrict__ wb,
    const float* __restrict__ ub, const float* __restrict__ vb,
    bf16* __restrict__ u_t, bf16* __restrict__ v_t)
{
    __shared__ __align__(16) char smem[32768];
    __bf16 (*sA)[64] = (__bf16(*)[64])smem;
    __bf16 (*sB)[64] = (__bf16(*)[64])(smem + 16384);
    __bf16* ldst = (__bf16*)smem;   // [64][132] bounce
    int tid = threadIdx.x;
    int wv = tid >> 6, lane = tid & 63;
    int b = blockIdx.x;
    int chunk = b & 7;
    int s = b >> 3;
    int by = s / 9;
    int ntile = s - by * 9;
    int nbase = ntile * 128;
    int wr = wv >> 1, wc = wv & 1;
    int lrow = lane >> 3, lcol = lane & 7;
    size_t gbase = (size_t)chunk * NPC + by * 128;
    f32x4 acc[4][4] = {};
    for (int kk = 0; kk < 3; ++kk) {
        #pragma unroll
        for (int i = 0; i < 4; ++i) {
            int row = wv * 32 + i * 8;
            gload16((const char*)(xbn + (gbase + row + lrow) * NE + kk * 64) + lcol * 16,
                    &sA[row][0]);
            gload16((const char*)(wb + (size_t)(nbase + row + lrow) * NE + kk * 64) + lcol * 16,
                    &sB[row][0]);
        }
        asm volatile("s_waitcnt vmcnt(0)" ::: "memory");
        __syncthreads();
        int q = lane >> 4, fr = lane & 15;
        #pragma unroll
        for (int k2 = 0; k2 < 2; ++k2) {
            bf16x8 af[4], bw[4];
            #pragma unroll
            for (int m = 0; m < 4; ++m) {
                int frm = wr * 64 + m * 16 + fr;
                af[m] = *(const bf16x8*)&sA[frm][(((k2 << 2) | q) ^ (frm & 7)) * 8];
            }
            #pragma unroll
            for (int n = 0; n < 4; ++n) {
                int fn = wc * 64 + n * 16 + fr;
                bw[n] = *(const bf16x8*)&sB[fn][(((k2 << 2) | q) ^ (fn & 7)) * 8];
            }
            #pragma unroll
            for (int m = 0; m < 4; ++m)
                #pragma unroll
                for (int n = 0; n < 4; ++n)
                    acc[m][n] = __builtin_amdgcn_mfma_f32_16x16x32_bf16(af[m], bw[n], acc[m][n], 0, 0, 0);
        }
        __syncthreads();
    }
    int fr = lane & 15, fq = lane >> 4;
    size_t pgl = gbase + (tid & 15) * 8;
    #pragma unroll
    for (int h = 0; h < 2; ++h) {
        if (wc == h) {
            #pragma unroll
            for (int m = 0; m < 4; ++m) {
                #pragma unroll
                for (int n = 0; n < 4; ++n) {
                    int row = n * 16 + fr;
                    int jn_g = nbase + h * 64 + row;
                    float bias = (jn_g < ND) ? ub[jn_g] : vb[jn_g - ND];
                    bf16x4 val;
                    #pragma unroll
                    for (int j = 0; j < 4; ++j) {
                        float z = acc[m][n][j] + bias;
                        float sgl = z * __builtin_amdgcn_rcpf(1.f + __expf(-z));
                        val[j] = (__bf16)sgl;
                    }
                    *(bf16x4*)&ldst[row * 132 + wr * 64 + m * 16 + fq * 4] = val;
                }
            }
        }
        __syncthreads();
        #pragma unroll
        for (int pass = 0; pass < 4; ++pass) {
            int row = (tid >> 4) + pass * 16;
            int jn_g = nbase + h * 64 + row;
            int colb = (tid & 15) * 8;
            bf16x4 a = *(bf16x4*)&ldst[row * 132 + colb];
            bf16x4 bb = *(bf16x4*)&ldst[row * 132 + colb + 4];
            bf16x8 o;
            #pragma unroll
            for (int i = 0; i < 4; ++i) { o[i] = a[i]; o[i + 4] = bb[i]; }
            __bf16* dst = (jn_g < ND) ? (__bf16*)u_t + (size_t)jn_g * NP + pgl
                                      : (__bf16*)v_t + (size_t)(jn_g - ND) * NP + pgl;
            *(bf16x8*)dst = o;
        }
        __syncthreads();
    }
}

// ---------------- fused MFMA Toeplitz conv (W + H) + gate ----------------
// r13-proven structure + partial T14: prefetch first 4 u-gate rows early
// (16 VGPR, stays below the 3-waves/SIMD boundary).
__global__ __launch_bounds__(256) void k_conv(
    bf16* __restrict__ v_t, const bf16* __restrict__ T, const bf16* __restrict__ u_t)
{
    __shared__ __bf16 Vp[128][132];
    int tid = threadIdx.x;
    int b = blockIdx.x;
    int c = (b & 7) * 72 + ((b >> 3) >> 3);
    int chunk = (b >> 3) & 7;
    size_t pbase = (size_t)c * NP + (size_t)chunk * NPC;
    const __bf16* vsrc = (const __bf16*)v_t + pbase;
    #pragma unroll
    for (int it = 0; it < 8; ++it) {
        int y = (tid >> 4) + 16 * it;
        int x0 = (tid & 15) * 8;
        bf16x8 rd = __builtin_nontemporal_load((const bf16x8*)(vsrc + (size_t)y * 128 + x0));
        bf16x4 lo, hi;
        #pragma unroll
        for (int i = 0; i < 4; ++i) { lo[i] = rd[i]; hi[i] = rd[i + 4]; }
        *(bf16x4*)&Vp[y][x0]     = lo;
        *(bf16x4*)&Vp[y][x0 + 4] = hi;
    }
    // partial T14: first 4 u-gate rows issued early, consumed in epilogue
    const __bf16* usrc = (const __bf16*)u_t + pbase;
    bf16x8 upre[4];
    #pragma unroll
    for (int it = 0; it < 4; ++it)
        upre[it] = __builtin_nontemporal_load(
            (const bf16x8*)(usrc + (size_t)((tid >> 4) + 16 * it) * 128 + (tid & 15) * 8));
    __syncthreads();
    int wv = tid >> 6, lane = tid & 63;
    int wr = wv >> 1, wc = wv & 1;
    int fr = lane & 15, q = lane >> 4;
    const __bf16* T1 = (const __bf16*)T + (size_t)c * 16384;
    const __bf16* T2 = (const __bf16*)T + (size_t)(ND + c) * 16384;
    f32x4 acc[4][4] = {};
    #pragma unroll
    for (int k = 0; k < 4; ++k) {
        bf16x8 af[4], bw[4];
        #pragma unroll
        for (int m = 0; m < 4; ++m) {
            int row = wr * 64 + m * 16 + fr;
            bf16x4 a = *(const bf16x4*)&Vp[row][k * 32 + q * 8];
            bf16x4 bb = *(const bf16x4*)&Vp[row][k * 32 + q * 8 + 4];
            #pragma unroll
            for (int i = 0; i < 4; ++i) { af[m][i] = a[i]; af[m][i + 4] = bb[i]; }
        }
        #pragma unroll
        for (int n = 0; n < 4; ++n)
            bw[n] = *(const bf16x8*)(T1 + (size_t)(wc * 64 + n * 16 + fr) * 128 + k * 32 + q * 8);
        #pragma unroll
        for (int m = 0; m < 4; ++m)
            #pragma unroll
            for (int n = 0; n < 4; ++n)
                acc[m][n] = __builtin_amdgcn_mfma_f32_16x16x32_bf16(af[m], bw[n], acc[m][n], 0, 0, 0);
    }
    #pragma unroll
    for (int k = 0; k < 4; ++k) {
        bf16x8 a2[4], b2[4];
        #pragma unroll
        for (int m = 0; m < 4; ++m)
            a2[m] = *(const bf16x8*)(T2 + (size_t)(wr * 64 + m * 16 + fr) * 128 + k * 32 + q * 8);
        #pragma unroll
        for (int n = 0; n < 4; ++n) {
            int xc = wc * 64 + n * 16 + fr;
            #pragma unroll
            for (int j = 0; j < 8; ++j)
                b2[n][j] = Vp[k * 32 + q * 8 + j][xc];
        }
        #pragma unroll
        for (int m = 0; m < 4; ++m)
            #pragma unroll
            for (int n = 0; n < 4; ++n)
                acc[m][n] = __builtin_amdgcn_mfma_f32_16x16x32_bf16(a2[m], b2[n], acc[m][n], 0, 0, 0);
    }
    __syncthreads();
    #pragma unroll
    for (int m = 0; m < 4; ++m) {
        #pragma unroll
        for (int n = 0; n < 4; ++n) {
            int xc = wc * 64 + n * 16 + fr;
            #pragma unroll
            for (int j = 0; j < 4; ++j) {
                int y = wr * 64 + m * 16 + q * 4 + j;
                Vp[y][xc] = (__bf16)acc[m][n][j];
            }
        }
    }
    __syncthreads();
    __bf16* vdst = (__bf16*)v_t + pbase;
    #pragma unroll
    for (int it = 0; it < 8; ++it) {
        int y = (tid >> 4) + 16 * it;
        int x0 = (tid & 15) * 8;
        bf16x8 uu = (it < 4) ? upre[it]
                   : __builtin_nontemporal_load((const bf16x8*)(usrc + (size_t)y * 128 + x0));
        bf16x4 lo = *(const bf16x4*)&Vp[y][x0];
        bf16x4 hi = *(const bf16x4*)&Vp[y][x0 + 4];
        bf16x8 o;
        #pragma unroll
        for (int i = 0; i < 4; ++i) {
            o[i]     = (__bf16)((float)uu[i]     * (float)lo[i]);
            o[i + 4] = (__bf16)((float)uu[i + 4] * (float)hi[i]);
        }
        __builtin_nontemporal_store(o, (bf16x8*)(vdst + (size_t)y * 128 + x0));
    }
}

// ---------------- final MFMA GEMM from channel-major g ----------------
// grid 2048 linear, XCD-paired E-split (r13-proven).
__global__ __launch_bounds__(256) void k_out(
    const bf16* __restrict__ g_t, const bf16* __restrict__ owb,
    const float* __restrict__ ob, const float* __restrict__ x, float* __restrict__ out)
{
    __shared__ __bf16 gs[64][132];
    int tid = threadIdx.x;
    int b = blockIdx.x;
    int xcd = b & 7, s = b >> 3;
    int eh = s & 1;
    int pt = xcd * 128 + (s >> 1);
    int wv = tid >> 6, lane = tid & 63;
    int wr = wv >> 1, wc = wv & 1;
    int fr = lane & 15, q = lane >> 4;
    int ebase = eh * 96 + wc * 48;
    f32x4 acc[4][3] = {};
    for (int kk = 0; kk < 9; ++kk) {
        #pragma unroll
        for (int i = 0; i < 4; ++i) {
            int cl = (tid >> 4) + 16 * i;
            int pg = (tid & 15) * 8;
            bf16x8 rd = *(const bf16x8*)((const __bf16*)g_t + (size_t)(kk * 64 + cl) * NP
                                         + (size_t)pt * 128 + pg);
            bf16x4 lo, hi;
            #pragma unroll
            for (int ii = 0; ii < 4; ++ii) { lo[ii] = rd[ii]; hi[ii] = rd[ii + 4]; }
            *(bf16x4*)&gs[cl][pg]     = lo;
            *(bf16x4*)&gs[cl][pg + 4] = hi;
        }
        __syncthreads();
        #pragma unroll
        for (int ks = 0; ks < 2; ++ks) {
            bf16x8 af[4], bw[3];
            #pragma unroll
            for (int m = 0; m < 4; ++m) {
                int prow = wr * 64 + m * 16 + fr;
                #pragma unroll
                for (int j = 0; j < 8; ++j)
                    af[m][j] = gs[ks * 32 + q * 8 + j][prow];
            }
            #pragma unroll
            for (int n = 0; n < 3; ++n) {
                int e = ebase + n * 16 + fr;
                bw[n] = *(const bf16x8*)((const __bf16*)owb + (size_t)e * ND + kk * 64 + ks * 32 + q * 8);
            }
            #pragma unroll
            for (int m = 0; m < 4; ++m)
                #pragma unroll
                for (int n = 0; n < 3; ++n)
                    acc[m][n] = __builtin_amdgcn_mfma_f32_16x16x32_bf16(af[m], bw[n], acc[m][n], 0, 0, 0);
        }
        __syncthreads();
    }
    #pragma unroll
    for (int m = 0; m < 4; ++m) {
        #pragma unroll
        for (int n = 0; n < 3; ++n) {
            int e = ebase + n * 16 + fr;
            float bias = ob[e];
            #pragma unroll
            for (int j = 0; j < 4; ++j) {
                size_t p = (size_t)pt * 128 + wr * 64 + m * 16 + q * 4 + j;
                float xv = __builtin_nontemporal_load(x + p * NE + e);
                __builtin_nontemporal_store(acc[m][n][j] + bias + xv, out + p * NE + e);
            }
        }
    }
}

extern "C" void kernel_launch(void* const* d_in, const int* in_sizes, int n_in,
                              void* d_out, int out_size, void* d_ws, size_t ws_size,
                              hipStream_t stream)
{
    const float* x    = (const float*)d_in[0];
    const float* u_w  = (const float*)d_in[1];
    const float* u_b  = (const float*)d_in[2];
    const float* v_w  = (const float*)d_in[3];
    const float* v_b  = (const float*)d_in[4];
    const float* o_w  = (const float*)d_in[5];
    const float* o_b  = (const float*)d_in[6];
    const float* r1_pw = (const float*)d_in[7];
    const float* r1_pb = (const float*)d_in[8];
    const float* r1_lw = (const float*)d_in[9];
    const float* r1_lb = (const float*)d_in[10];
    const float* r1_ow = (const float*)d_in[11];
    const float* r1_ob = (const float*)d_in[12];
    const float* r2_pw = (const float*)d_in[13];
    const float* r2_pb = (const float*)d_in[14];
    const float* r2_lw = (const float*)d_in[15];
    const float* r2_lb = (const float*)d_in[16];
    const float* r2_ow = (const float*)d_in[17];
    const float* r2_ob = (const float*)d_in[18];
    float* out = (float*)d_out;

    // ---- workspace layout ----
    float* A1  = (float*)d_ws;                         // NL*ND
    float* A2  = A1 + (size_t)NL * ND;                 // NL*ND
    bf16* wb   = (bf16*)(A2 + (size_t)NL * ND);        // 1152*192 (pre-swizzled)
    bf16* owb  = wb + (size_t)2 * ND * NE;             // 192*576
    bf16* u_t  = owb + (size_t)NE * ND;                // ND*NP
    bf16* v_t  = u_t + (size_t)ND * NP;                // ND*NP
    bf16* xbn  = v_t + (size_t)ND * NP;                // NP*NE (pre-swizzled)
    float* h0 = (float*)(xbn + (size_t)NP * NE);       // 2*NL*NR (overlay)
    float* h1 = h0 + (size_t)2 * NL * NR;              // 2*NL*NR
    float* wt = h1 + (size_t)2 * NL * NR;              // 2*1081344
    bf16* T   = (bf16*)h0;                             // 2*576*16384 (after RPE done)

    k_pre1<<<dim3(2816), dim3(256), 0, stream>>>(
        r1_pw, r1_pb, r2_pw, r2_pb, r1_lw, r1_ow, r2_lw, r2_ow, h0, wt);
    {
        const float* src[3] = { h0, h1, h0 };
        float* dst[3]       = { h1, h0, h1 };
        for (int i = 0; i < 3; ++i) {
            k_rpe_layer<<<dim3(256), dim3(256), 0, stream>>>(
                src[i], wt + (size_t)i * 262144, r1_lb + (size_t)i * NR,
                        wt + 1081344 + (size_t)i * 262144, r2_lb + (size_t)i * NR,
                dst[i], dst[i] + (size_t)NL * NR, NR);
        }
        k_rpe_layer<<<dim3(256), dim3(256), 0, stream>>>(
            h1, wt + 786432, r1_ob, wt + 1081344 + 786432, r2_ob, A1, A2, ND);
    }
    k_pre2<<<dim3(33272), dim3(256), 0, stream>>>(
        x, xbn, A1, A2, T, u_w, v_w, o_w, wb, owb);

    k_uv<<<dim3(9216), dim3(256), 0, stream>>>(xbn, wb, u_b, v_b, u_t, v_t);
    k_conv<<<dim3(4608), dim3(256), 0, stream>>>(v_t, T, u_t);
    k_out<<<dim3(2048), dim3(256), 0, stream>>>(v_t, owb, o_b, x, out);
}

// Round 18
// 530.938 us; speedup vs baseline: 1.0349x; 1.0349x over previous
//
#include <hip/hip_runtime.h>
#include <hip/hip_bf16.h>

typedef __hip_bfloat16 bf16;
typedef __attribute__((ext_vector_type(4))) float f32x4;
typedef __attribute__((ext_vector_type(8))) __bf16 bf16x8;
typedef __attribute__((ext_vector_type(4))) __bf16 bf16x4;

constexpr int NB  = 8;
constexpr int NHH = 128;
constexpr int NWW = 128;
constexpr int NE  = 192;
constexpr int ND  = 576;
constexpr int NR  = 512;
constexpr int NL  = 256;
constexpr int NP  = NB * NHH * NWW;   // 131072
constexpr int NPC = NHH * NWW;        // 16384

__device__ __forceinline__ void gload16(const void* g, void* l) {
    __builtin_amdgcn_global_load_lds(
        (const __attribute__((address_space(1))) unsigned int*)g,
        (__attribute__((address_space(3))) unsigned int*)l, 16, 0, 0);
}

// ---------------- merged: RPE pos (b<512) + RPE weight transpose ----------------
__global__ __launch_bounds__(256) void k_pre1(
    const float* __restrict__ pw1, const float* __restrict__ pb1,
    const float* __restrict__ pw2, const float* __restrict__ pb2,
    const float* __restrict__ lw1, const float* __restrict__ ow1,
    const float* __restrict__ lw2, const float* __restrict__ ow2,
    float* __restrict__ h, float* __restrict__ wt)
{
    __shared__ float tile[32][33];
    int b = blockIdx.x;
    if (b < 512) {
        int net = b >> 8, l = b & 255;
        const float* pw = net ? pw2 : pw1;
        const float* pb = net ? pb2 : pb1;
        float idxv;
        if (l == 0 || l == 128) idxv = 0.f;
        else if (l < 128)       idxv = (float)l;
        else                    idxv = (float)(l - 256);
        float* hr = h + ((size_t)net * NL + l) * NR;
        for (int r = threadIdx.x; r < NR; r += 256)
            hr[r] = idxv * pw[r] + pb[r];
    } else {
        int idx = b - 512;                 // 2304 blocks: m(8) x jb(18) x rb(16)
        int m = idx / 288;
        int rem = idx - m * 288;
        int jb = rem >> 4, rb = rem & 15;
        int net = m >> 2, sub = m & 3;
        int J = (sub == 3) ? 576 : 512;
        const float* src = (sub == 3) ? (net ? ow2 : ow1)
                                      : (net ? lw2 : lw1) + (size_t)sub * 262144;
        float* dst = wt + (size_t)net * 1081344 + ((sub == 3) ? 786432 : sub * 262144);
        int r0 = rb * 32, j0 = jb * 32;
        if (j0 >= J) return;
        int tx = threadIdx.x & 31, ty = threadIdx.x >> 5;
        #pragma unroll
        for (int d = 0; d < 4; ++d) {
            int j = j0 + ty + d * 8;
            tile[ty + d * 8][tx] = (j < J) ? src[(size_t)j * 512 + r0 + tx] : 0.f;
        }
        __syncthreads();
        #pragma unroll
        for (int d = 0; d < 4; ++d) {
            int r = r0 + ty + d * 8;
            int j = j0 + tx;
            if (j < J) dst[(size_t)r * J + j] = tile[tx][ty + d * 8];
        }
    }
}

// ---------------- RPE layer: out = relu(srms(h)) @ Wt + b ----------------
__global__ __launch_bounds__(256) void k_rpe_layer(
    const float* __restrict__ hin,
    const float* __restrict__ Wt1, const float* __restrict__ b1,
    const float* __restrict__ Wt2, const float* __restrict__ b2,
    float* __restrict__ out1, float* __restrict__ out2, int outdim)
{
    __shared__ float g[2][NR];
    __shared__ float red[256];
    int net = blockIdx.x >> 7;
    int l0  = (blockIdx.x & 127) * 2;
    const float* hr = hin + ((size_t)net * NL + l0) * NR;
    int tid = threadIdx.x;
    int row = tid >> 7, ix = tid & 127;
    const float* hh = hr + (size_t)row * NR;
    float a0 = hh[ix], a1 = hh[ix + 128], a2 = hh[ix + 256], a3 = hh[ix + 384];
    red[tid] = a0 * a0 + a1 * a1 + a2 * a2 + a3 * a3;
    __syncthreads();
    for (int off = 64; off; off >>= 1) {
        if (ix < off) red[tid] += red[tid + off];
        __syncthreads();
    }
    float sc = 1.f / (sqrtf(red[row << 7]) * 0.044194173824159216f + 1e-8f);  // d=512
    g[row][ix]       = fmaxf(a0 * sc, 0.f);
    g[row][ix + 128] = fmaxf(a1 * sc, 0.f);
    g[row][ix + 256] = fmaxf(a2 * sc, 0.f);
    g[row][ix + 384] = fmaxf(a3 * sc, 0.f);
    __syncthreads();
    const float* Wt = net ? Wt2 : Wt1;
    const float* bb = net ? b2 : b1;
    float* o0 = (net ? out2 : out1) + (size_t)l0 * outdim;
    int half = outdim >> 1;
    for (int jj = tid; jj < half; jj += 256) {
        float ax0 = 0.f, ay0 = 0.f, ax1 = 0.f, ay1 = 0.f;
        const float* wp = Wt + 2 * jj;
        #pragma unroll 8
        for (int r = 0; r < NR; ++r) {
            float2 w = *(const float2*)(wp + (size_t)r * outdim);
            float g0 = g[0][r], g1 = g[1][r];
            ax0 = fmaf(g0, w.x, ax0); ay0 = fmaf(g0, w.y, ay0);
            ax1 = fmaf(g1, w.x, ax1); ay1 = fmaf(g1, w.y, ay1);
        }
        float bx = bb[2 * jj], by = bb[2 * jj + 1];
        o0[2 * jj]              = ax0 + bx;  o0[2 * jj + 1]          = ay0 + by;
        o0[outdim + 2 * jj]     = ax1 + bx;  o0[outdim + 2 * jj + 1] = ay1 + by;
    }
}

// ---------------- merged: prep (b<32768) + toep + wconv ----------------
__global__ __launch_bounds__(256) void k_pre2(
    const float* __restrict__ x, bf16* __restrict__ xbn,
    const float* __restrict__ A1, const float* __restrict__ A2, bf16* __restrict__ T,
    const float* __restrict__ uw, const float* __restrict__ vw,
    const float* __restrict__ ow, bf16* __restrict__ wb, bf16* __restrict__ owb)
{
    __shared__ __align__(16) char sm[17408];
    int b = blockIdx.x;
    int tid = threadIdx.x;
    if (b < 32768) {
        __bf16 (*wbuf)[208] = (__bf16(*)[208])sm;
        int w = tid >> 6, lane = tid & 63;
        int p = b * 4 + w;
        const float* xp = x + (size_t)p * NE;
        float v0 = xp[lane], v1 = xp[lane + 64], v2 = xp[lane + 128];
        float ss = v0 * v0 + v1 * v1 + v2 * v2;
        for (int off = 32; off; off >>= 1) ss += __shfl_xor(ss, off, 64);
        float sc = __builtin_amdgcn_rcpf(sqrtf(ss) * 0.07216878364870323f + 1e-8f);
        wbuf[w][lane]       = (__bf16)(v0 * sc);
        wbuf[w][lane + 64]  = (__bf16)(v1 * sc);
        wbuf[w][lane + 128] = (__bf16)(v2 * sc);
        __syncthreads();
        if (lane < 24) {
            bf16x8 o = *(bf16x8*)&wbuf[w][lane * 8];
            int t = (lane & 24) | ((lane & 7) ^ (p & 7));
            *(bf16x8*)((__bf16*)xbn + (size_t)p * NE + t * 8) = o;
        }
    } else if (b < 32768 + 288) {
        float (*Als)[17] = (float(*)[17])sm;
        int i = b - 32768;
        int cb = i % 36, rq = (i / 36) & 3, net = i / 144;
        const float* A = net ? A2 : A1;
        #pragma unroll
        for (int it = 0; it < 16; ++it) {
            int el = it * 256 + tid;
            int k = el >> 4, cl = el & 15;
            Als[k][cl] = A[(size_t)k * ND + cb * 16 + cl];
        }
        __syncthreads();
        int cl = tid >> 4, sg = tid & 15;
        __bf16* Tb = (__bf16*)T + (((size_t)net * ND + cb * 16 + cl) * 128) * 128;
        for (int rr = 0; rr < 32; ++rr) {
            int r = rq * 32 + rr;
            bf16x8 o;
            #pragma unroll
            for (int j = 0; j < 8; ++j)
                o[j] = (__bf16)Als[(r - sg * 8 - j) & 255][cl];
            *(bf16x8*)(Tb + (size_t)r * 128 + sg * 8) = o;
        }
    } else {
        int gid = (b - 33056) * 256 + tid;
        if (gid < 27648) {
            int row = gid / 24, bb = gid - row * 24;
            const float* src = ((row < ND) ? uw + (size_t)row * NE
                                           : vw + (size_t)(row - ND) * NE) + bb * 8;
            float4 f0 = ((const float4*)src)[0], f1 = ((const float4*)src)[1];
            bf16x8 o;
            o[0] = (__bf16)f0.x; o[1] = (__bf16)f0.y; o[2] = (__bf16)f0.z; o[3] = (__bf16)f0.w;
            o[4] = (__bf16)f1.x; o[5] = (__bf16)f1.y; o[6] = (__bf16)f1.z; o[7] = (__bf16)f1.w;
            int t = (bb & 24) | ((bb & 7) ^ (row & 7));
            *(bf16x8*)((__bf16*)wb + (size_t)row * NE + t * 8) = o;
        } else if (gid < 27648 + 13824) {
            int g = gid - 27648;
            const float* src = ow + (size_t)g * 8;
            float4 f0 = ((const float4*)src)[0], f1 = ((const float4*)src)[1];
            bf16x8 o;
            o[0] = (__bf16)f0.x; o[1] = (__bf16)f0.y; o[2] = (__bf16)f0.z; o[3] = (__bf16)f0.w;
            o[4] = (__bf16)f1.x; o[5] = (__bf16)f1.y; o[6] = (__bf16)f1.z; o[7] = (__bf16)f1.w;
            *(bf16x8*)((__bf16*)owb + (size_t)g * 8) = o;
        }
    }
}

// ---------------- u,v MFMA GEMM (all chunks), channel-major output ----------------
// single-phase epilogue with full [128][132] bounce (r16-measured best)
__global__ __launch_bounds__(256, 4) void k_uv(
    const bf16* __restrict__ xbn, const bf16* __restrict__ wb,
    const float* __restrict__ ub, const float* __restrict__ vb,
    bf16* __restrict__ u_t, bf16* __restrict__ v_t)
{
    __shared__ __align__(16) char smem[33792];
    __bf16 (*sA)[64] = (__bf16(*)[64])smem;
    __bf16 (*sB)[64] = (__bf16(*)[64])(smem + 16384);
    __bf16* ldst = (__bf16*)smem;   // [128][132] bounce (aliases sA/sB after main loop)
    int tid = threadIdx.x;
    int wv = tid >> 6, lane = tid & 63;
    int b = blockIdx.x;
    int chunk = b & 7;
    int s = b >> 3;
    int by = s / 9;
    int ntile = s - by * 9;
    int nbase = ntile * 128;
    int wr = wv >> 1, wc = wv & 1;
    int lrow = lane >> 3, lcol = lane & 7;
    size_t gbase = (size_t)chunk * NPC + by * 128;
    f32x4 acc[4][4] = {};
    for (int kk = 0; kk < 3; ++kk) {
        #pragma unroll
        for (int i = 0; i < 4; ++i) {
            int row = wv * 32 + i * 8;
            gload16((const char*)(xbn + (gbase + row + lrow) * NE + kk * 64) + lcol * 16,
                    &sA[row][0]);
            gload16((const char*)(wb + (size_t)(nbase + row + lrow) * NE + kk * 64) + lcol * 16,
                    &sB[row][0]);
        }
        asm volatile("s_waitcnt vmcnt(0)" ::: "memory");
        __syncthreads();
        int q = lane >> 4, fr = lane & 15;
        #pragma unroll
        for (int k2 = 0; k2 < 2; ++k2) {
            bf16x8 af[4], bw[4];
            #pragma unroll
            for (int m = 0; m < 4; ++m) {
                int frm = wr * 64 + m * 16 + fr;
                af[m] = *(const bf16x8*)&sA[frm][(((k2 << 2) | q) ^ (frm & 7)) * 8];
            }
            #pragma unroll
            for (int n = 0; n < 4; ++n) {
                int fn = wc * 64 + n * 16 + fr;
                bw[n] = *(const bf16x8*)&sB[fn][(((k2 << 2) | q) ^ (fn & 7)) * 8];
            }
            #pragma unroll
            for (int m = 0; m < 4; ++m)
                #pragma unroll
                for (int n = 0; n < 4; ++n)
                    acc[m][n] = __builtin_amdgcn_mfma_f32_16x16x32_bf16(af[m], bw[n], acc[m][n], 0, 0, 0);
        }
        __syncthreads();
    }
    // ---- single-phase transposed epilogue ----
    int fr = lane & 15, fq = lane >> 4;
    #pragma unroll
    for (int m = 0; m < 4; ++m) {
        #pragma unroll
        for (int n = 0; n < 4; ++n) {
            int row = wc * 64 + n * 16 + fr;
            int jn_g = nbase + row;
            float bias = (jn_g < ND) ? ub[jn_g] : vb[jn_g - ND];
            bf16x4 val;
            #pragma unroll
            for (int j = 0; j < 4; ++j) {
                float z = acc[m][n][j] + bias;
                float sgl = z * __builtin_amdgcn_rcpf(1.f + __expf(-z));
                val[j] = (__bf16)sgl;
            }
            *(bf16x4*)&ldst[row * 132 + wr * 64 + m * 16 + fq * 4] = val;
        }
    }
    __syncthreads();
    size_t pgl = gbase + (tid & 15) * 8;
    #pragma unroll
    for (int pass = 0; pass < 8; ++pass) {
        int row = (tid >> 4) + pass * 16;
        int jn_g = nbase + row;
        int colb = (tid & 15) * 8;
        bf16x4 a = *(bf16x4*)&ldst[row * 132 + colb];
        bf16x4 bb = *(bf16x4*)&ldst[row * 132 + colb + 4];
        bf16x8 o;
        #pragma unroll
        for (int i = 0; i < 4; ++i) { o[i] = a[i]; o[i + 4] = bb[i]; }
        __bf16* dst = (jn_g < ND) ? (__bf16*)u_t + (size_t)jn_g * NP + pgl
                                  : (__bf16*)v_t + (size_t)(jn_g - ND) * NP + pgl;
        *(bf16x8*)dst = o;
    }
}

// ---------------- fused MFMA Toeplitz conv (W + H) + gate ----------------
// r13/r16-proven config: grid 4608 linear, XCD-pinned, 256 thr, 2x2 wave tile,
// padded [132], NT hints, default launch bounds, NO prefetch.
__global__ __launch_bounds__(256) void k_conv(
    bf16* __restrict__ v_t, const bf16* __restrict__ T, const bf16* __restrict__ u_t)
{
    __shared__ __bf16 Vp[128][132];
    int tid = threadIdx.x;
    int b = blockIdx.x;
    int c = (b & 7) * 72 + ((b >> 3) >> 3);
    int chunk = (b >> 3) & 7;
    size_t pbase = (size_t)c * NP + (size_t)chunk * NPC;
    const __bf16* vsrc = (const __bf16*)v_t + pbase;
    #pragma unroll
    for (int it = 0; it < 8; ++it) {
        int y = (tid >> 4) + 16 * it;
        int x0 = (tid & 15) * 8;
        bf16x8 rd = __builtin_nontemporal_load((const bf16x8*)(vsrc + (size_t)y * 128 + x0));
        bf16x4 lo, hi;
        #pragma unroll
        for (int i = 0; i < 4; ++i) { lo[i] = rd[i]; hi[i] = rd[i + 4]; }
        *(bf16x4*)&Vp[y][x0]     = lo;
        *(bf16x4*)&Vp[y][x0 + 4] = hi;
    }
    __syncthreads();
    int wv = tid >> 6, lane = tid & 63;
    int wr = wv >> 1, wc = wv & 1;
    int fr = lane & 15, q = lane >> 4;
    const __bf16* T1 = (const __bf16*)T + (size_t)c * 16384;
    const __bf16* T2 = (const __bf16*)T + (size_t)(ND + c) * 16384;
    f32x4 acc[4][4] = {};
    #pragma unroll
    for (int k = 0; k < 4; ++k) {
        bf16x8 af[4], bw[4];
        #pragma unroll
        for (int m = 0; m < 4; ++m) {
            int row = wr * 64 + m * 16 + fr;
            bf16x4 a = *(const bf16x4*)&Vp[row][k * 32 + q * 8];
            bf16x4 bb = *(const bf16x4*)&Vp[row][k * 32 + q * 8 + 4];
            #pragma unroll
            for (int i = 0; i < 4; ++i) { af[m][i] = a[i]; af[m][i + 4] = bb[i]; }
        }
        #pragma unroll
        for (int n = 0; n < 4; ++n)
            bw[n] = *(const bf16x8*)(T1 + (size_t)(wc * 64 + n * 16 + fr) * 128 + k * 32 + q * 8);
        #pragma unroll
        for (int m = 0; m < 4; ++m)
            #pragma unroll
            for (int n = 0; n < 4; ++n)
                acc[m][n] = __builtin_amdgcn_mfma_f32_16x16x32_bf16(af[m], bw[n], acc[m][n], 0, 0, 0);
    }
    #pragma unroll
    for (int k = 0; k < 4; ++k) {
        bf16x8 a2[4], b2[4];
        #pragma unroll
        for (int m = 0; m < 4; ++m)
            a2[m] = *(const bf16x8*)(T2 + (size_t)(wr * 64 + m * 16 + fr) * 128 + k * 32 + q * 8);
        #pragma unroll
        for (int n = 0; n < 4; ++n) {
            int xc = wc * 64 + n * 16 + fr;
            #pragma unroll
            for (int j = 0; j < 8; ++j)
                b2[n][j] = Vp[k * 32 + q * 8 + j][xc];
        }
        #pragma unroll
        for (int m = 0; m < 4; ++m)
            #pragma unroll
            for (int n = 0; n < 4; ++n)
                acc[m][n] = __builtin_amdgcn_mfma_f32_16x16x32_bf16(a2[m], b2[n], acc[m][n], 0, 0, 0);
    }
    __syncthreads();
    #pragma unroll
    for (int m = 0; m < 4; ++m) {
        #pragma unroll
        for (int n = 0; n < 4; ++n) {
            int xc = wc * 64 + n * 16 + fr;
            #pragma unroll
            for (int j = 0; j < 4; ++j) {
                int y = wr * 64 + m * 16 + q * 4 + j;
                Vp[y][xc] = (__bf16)acc[m][n][j];
            }
        }
    }
    __syncthreads();
    const __bf16* usrc = (const __bf16*)u_t + pbase;
    __bf16* vdst = (__bf16*)v_t + pbase;
    #pragma unroll
    for (int it = 0; it < 8; ++it) {
        int y = (tid >> 4) + 16 * it;
        int x0 = (tid & 15) * 8;
        bf16x8 uu = __builtin_nontemporal_load((const bf16x8*)(usrc + (size_t)y * 128 + x0));
        bf16x4 lo = *(const bf16x4*)&Vp[y][x0];
        bf16x4 hi = *(const bf16x4*)&Vp[y][x0 + 4];
        bf16x8 o;
        #pragma unroll
        for (int i = 0; i < 4; ++i) {
            o[i]     = (__bf16)((float)uu[i]     * (float)lo[i]);
            o[i + 4] = (__bf16)((float)uu[i + 4] * (float)hi[i]);
        }
        __builtin_nontemporal_store(o, (bf16x8*)(vdst + (size_t)y * 128 + x0));
    }
}

// ---------------- final MFMA GEMM from channel-major g ----------------
// grid 2048 linear, XCD-paired E-split (r13-proven).
__global__ __launch_bounds__(256) void k_out(
    const bf16* __restrict__ g_t, const bf16* __restrict__ owb,
    const float* __restrict__ ob, const float* __restrict__ x, float* __restrict__ out)
{
    __shared__ __bf16 gs[64][132];
    int tid = threadIdx.x;
    int b = blockIdx.x;
    int xcd = b & 7, s = b >> 3;
    int eh = s & 1;
    int pt = xcd * 128 + (s >> 1);
    int wv = tid >> 6, lane = tid & 63;
    int wr = wv >> 1, wc = wv & 1;
    int fr = lane & 15, q = lane >> 4;
    int ebase = eh * 96 + wc * 48;
    f32x4 acc[4][3] = {};
    for (int kk = 0; kk < 9; ++kk) {
        #pragma unroll
        for (int i = 0; i < 4; ++i) {
            int cl = (tid >> 4) + 16 * i;
            int pg = (tid & 15) * 8;
            bf16x8 rd = *(const bf16x8*)((const __bf16*)g_t + (size_t)(kk * 64 + cl) * NP
                                         + (size_t)pt * 128 + pg);
            bf16x4 lo, hi;
            #pragma unroll
            for (int ii = 0; ii < 4; ++ii) { lo[ii] = rd[ii]; hi[ii] = rd[ii + 4]; }
            *(bf16x4*)&gs[cl][pg]     = lo;
            *(bf16x4*)&gs[cl][pg + 4] = hi;
        }
        __syncthreads();
        #pragma unroll
        for (int ks = 0; ks < 2; ++ks) {
            bf16x8 af[4], bw[3];
            #pragma unroll
            for (int m = 0; m < 4; ++m) {
                int prow = wr * 64 + m * 16 + fr;
                #pragma unroll
                for (int j = 0; j < 8; ++j)
                    af[m][j] = gs[ks * 32 + q * 8 + j][prow];
            }
            #pragma unroll
            for (int n = 0; n < 3; ++n) {
                int e = ebase + n * 16 + fr;
                bw[n] = *(const bf16x8*)((const __bf16*)owb + (size_t)e * ND + kk * 64 + ks * 32 + q * 8);
            }
            #pragma unroll
            for (int m = 0; m < 4; ++m)
                #pragma unroll
                for (int n = 0; n < 3; ++n)
                    acc[m][n] = __builtin_amdgcn_mfma_f32_16x16x32_bf16(af[m], bw[n], acc[m][n], 0, 0, 0);
        }
        __syncthreads();
    }
    #pragma unroll
    for (int m = 0; m < 4; ++m) {
        #pragma unroll
        for (int n = 0; n < 3; ++n) {
            int e = ebase + n * 16 + fr;
            float bias = ob[e];
            #pragma unroll
            for (int j = 0; j < 4; ++j) {
                size_t p = (size_t)pt * 128 + wr * 64 + m * 16 + q * 4 + j;
                float xv = __builtin_nontemporal_load(x + p * NE + e);
                __builtin_nontemporal_store(acc[m][n][j] + bias + xv, out + p * NE + e);
            }
        }
    }
}

extern "C" void kernel_launch(void* const* d_in, const int* in_sizes, int n_in,
                              void* d_out, int out_size, void* d_ws, size_t ws_size,
                              hipStream_t stream)
{
    const float* x    = (const float*)d_in[0];
    const float* u_w  = (const float*)d_in[1];
    const float* u_b  = (const float*)d_in[2];
    const float* v_w  = (const float*)d_in[3];
    const float* v_b  = (const float*)d_in[4];
    const float* o_w  = (const float*)d_in[5];
    const float* o_b  = (const float*)d_in[6];
    const float* r1_pw = (const float*)d_in[7];
    const float* r1_pb = (const float*)d_in[8];
    const float* r1_lw = (const float*)d_in[9];
    const float* r1_lb = (const float*)d_in[10];
    const float* r1_ow = (const float*)d_in[11];
    const float* r1_ob = (const float*)d_in[12];
    const float* r2_pw = (const float*)d_in[13];
    const float* r2_pb = (const float*)d_in[14];
    const float* r2_lw = (const float*)d_in[15];
    const float* r2_lb = (const float*)d_in[16];
    const float* r2_ow = (const float*)d_in[17];
    const float* r2_ob = (const float*)d_in[18];
    float* out = (float*)d_out;

    // ---- workspace layout ----
    float* A1  = (float*)d_ws;                         // NL*ND
    float* A2  = A1 + (size_t)NL * ND;                 // NL*ND
    bf16* wb   = (bf16*)(A2 + (size_t)NL * ND);        // 1152*192 (pre-swizzled)
    bf16* owb  = wb + (size_t)2 * ND * NE;             // 192*576
    bf16* u_t  = owb + (size_t)NE * ND;                // ND*NP
    bf16* v_t  = u_t + (size_t)ND * NP;                // ND*NP
    bf16* xbn  = v_t + (size_t)ND * NP;                // NP*NE (pre-swizzled)
    float* h0 = (float*)(xbn + (size_t)NP * NE);       // 2*NL*NR (overlay)
    float* h1 = h0 + (size_t)2 * NL * NR;              // 2*NL*NR
    float* wt = h1 + (size_t)2 * NL * NR;              // 2*1081344
    bf16* T   = (bf16*)h0;                             // 2*576*16384 (after RPE done)

    k_pre1<<<dim3(2816), dim3(256), 0, stream>>>(
        r1_pw, r1_pb, r2_pw, r2_pb, r1_lw, r1_ow, r2_lw, r2_ow, h0, wt);
    {
        const float* src[3] = { h0, h1, h0 };
        float* dst[3]       = { h1, h0, h1 };
        for (int i = 0; i < 3; ++i) {
            k_rpe_layer<<<dim3(256), dim3(256), 0, stream>>>(
                src[i], wt + (size_t)i * 262144, r1_lb + (size_t)i * NR,
                        wt + 1081344 + (size_t)i * 262144, r2_lb + (size_t)i * NR,
                dst[i], dst[i] + (size_t)NL * NR, NR);
        }
        k_rpe_layer<<<dim3(256), dim3(256), 0, stream>>>(
            h1, wt + 786432, r1_ob, wt + 1081344 + 786432, r2_ob, A1, A2, ND);
    }
    k_pre2<<<dim3(33272), dim3(256), 0, stream>>>(
        x, xbn, A1, A2, T, u_w, v_w, o_w, wb, owb);

    k_uv<<<dim3(9216), dim3(256), 0, stream>>>(xbn, wb, u_b, v_b, u_t, v_t);
    k_conv<<<dim3(4608), dim3(256), 0, stream>>>(v_t, T, u_t);
    k_out<<<dim3(2048), dim3(256), 0, stream>>>(v_t, owb, o_b, x, out);
}